// Round 11
// baseline (341.455 us; speedup 1.0000x reference)
//
#include <hip/hip_runtime.h>
#include <hip/hip_bf16.h>
#include <stdint.h>

#define N_NODES 100000
#define N_EDGES 1280000
#define IN_DIM  256
#define OUT_DIM 64
#define NB1     98          // ceil(100000/1024) scan blocks
#define GEMM_BLOCKS ((N_NODES + 63) / 64)   // 1563

// zero-global-atomic histogram: 4 bin-slices x 50 edge-chunks
#define HSL   4             // slices of 25000 bins (50 KB packed-u16 LDS)
#define HSB   25000         // bins per slice
#define HCH   50            // edge chunks
#define HEPC  (N_EDGES / HCH)   // 25600 edges per chunk (< 65536: u16-safe)

// reorder: 8 node-slices x 50 chunks, all 400 blocks co-resident
#define RSL   8
#define RSN   (N_NODES / RSL)    // 12500 nodes per slice

typedef __attribute__((ext_vector_type(8))) short bf16x8;
typedef __attribute__((ext_vector_type(4))) float f32x4;
typedef __attribute__((ext_vector_type(4))) unsigned short u16x4;
typedef __attribute__((ext_vector_type(4))) int i32x4;

__device__ __forceinline__ unsigned short f32_to_bf16(float f) {
    union { float f; unsigned int u; } c; c.f = f;
    unsigned int u = c.u;
    u += 0x7fffu + ((u >> 16) & 1u);   // RNE
    return (unsigned short)(u >> 16);
}
__device__ __forceinline__ float bf16_to_f32(unsigned short h) {
    union { unsigned int u; float f; } c; c.u = ((unsigned int)h) << 16; return c.f;
}

// ---------------------------------------------------------------------------
// K0: one-time W pack (f32 -> bf16, B-fragment order), 16 blocks.
// ---------------------------------------------------------------------------
__global__ __launch_bounds__(256) void wpack_kernel(const float* __restrict__ w,
                                                    unsigned short* __restrict__ wbf) {
    const int i0 = blockIdx.x * 1024;
    for (int i = i0 + threadIdx.x; i < i0 + 1024; i += 256) {
        const int k = i >> 6, n = i & 63;
        const int kt = k >> 5, q = (k >> 3) & 3, j = k & 7;
        const int t = n >> 4, l = n & 15;
        wbf[((kt * 4 + t) * 64 + q * 16 + l) * 8 + j] = f32_to_bf16(w[i]);
    }
}

// ---------------------------------------------------------------------------
// K_hist: zero-global-atomic histogram (round-8, proven). Block (slice s,
// chunk c) LDS-counts chunk c's rows in bin-slice s as packed u16 pairs,
// writes a non-atomic u16 partial stripe. scan1 sums the 50 partials.
// ---------------------------------------------------------------------------
__global__ __launch_bounds__(256) void hist_kernel(const int* __restrict__ rows,
                                                   unsigned short* __restrict__ partial) {
    __shared__ unsigned int lh[HSB / 2];          // 50 KB
    const int s = blockIdx.x & 3;                 // slice
    const int c = blockIdx.x >> 2;                // chunk
    const int lo = s * HSB;
    for (int i = threadIdx.x; i < HSB / 2; i += 256) lh[i] = 0u;
    __syncthreads();
    const i32x4* rp = (const i32x4*)(rows + c * HEPC);
    for (int i = threadIdx.x; i < HEPC / 4; i += 256) {   // 25 iterations
        const i32x4 r4 = rp[i];
        const unsigned d0 = (unsigned)(r4.x - lo);
        const unsigned d1 = (unsigned)(r4.y - lo);
        const unsigned d2 = (unsigned)(r4.z - lo);
        const unsigned d3 = (unsigned)(r4.w - lo);
        if (d0 < HSB) atomicAdd(&lh[d0 >> 1], 1u << ((d0 & 1) * 16));
        if (d1 < HSB) atomicAdd(&lh[d1 >> 1], 1u << ((d1 & 1) * 16));
        if (d2 < HSB) atomicAdd(&lh[d2 >> 1], 1u << ((d2 & 1) * 16));
        if (d3 < HSB) atomicAdd(&lh[d3 >> 1], 1u << ((d3 & 1) * 16));
    }
    __syncthreads();
    unsigned int* dst = (unsigned int*)(partial + (size_t)c * N_NODES + lo);
    for (int i = threadIdx.x; i < HSB / 2; i += 256) dst[i] = lh[i];
}

// ---------------------------------------------------------------------------
// K1: GEMM (round-2 proven structure, unchanged).
// ---------------------------------------------------------------------------
__global__ __launch_bounds__(256, 4) void gemm_kernel(const float* __restrict__ x,
                                                      const unsigned short* __restrict__ wbf,
                                                      unsigned short* __restrict__ pre) {
    __shared__ __align__(16) unsigned short wt[IN_DIM * OUT_DIM];   // 32 KB

    const int tid = threadIdx.x;
    const int wave = tid >> 6;
    const int lane = tid & 63;
    const int ln16 = lane & 15;
    const int quad = lane >> 4;

    const int R0 = blockIdx.x * 64;
    const int arow = R0 + wave * 16 + ln16;
    const float* xrow = x + (size_t)(arow < N_NODES ? arow : N_NODES - 1) * IN_DIM + quad * 8;

    f32x4 xa[8], xb[8];
    #pragma unroll
    for (int kt = 0; kt < 8; ++kt) {
        xa[kt] = *(const f32x4*)(xrow + kt * 32);
        xb[kt] = *(const f32x4*)(xrow + kt * 32 + 4);
    }

    #pragma unroll
    for (int i = 0; i < 8; ++i)
        *(bf16x8*)&wt[i * 2048 + tid * 8] = *(const bf16x8*)(wbf + i * 2048 + tid * 8);

    __syncthreads();

    f32x4 acc[4] = {};

    #pragma unroll
    for (int kt = 0; kt < 8; ++kt) {
        bf16x8 a;
        a[0] = (short)f32_to_bf16(xa[kt].x); a[1] = (short)f32_to_bf16(xa[kt].y);
        a[2] = (short)f32_to_bf16(xa[kt].z); a[3] = (short)f32_to_bf16(xa[kt].w);
        a[4] = (short)f32_to_bf16(xb[kt].x); a[5] = (short)f32_to_bf16(xb[kt].y);
        a[6] = (short)f32_to_bf16(xb[kt].z); a[7] = (short)f32_to_bf16(xb[kt].w);
        #pragma unroll
        for (int t = 0; t < 4; ++t) {
            bf16x8 b = *(const bf16x8*)&wt[((kt * 4 + t) * 64 + lane) * 8];
            acc[t] = __builtin_amdgcn_mfma_f32_16x16x32_bf16(a, b, acc[t], 0, 0, 0);
        }
    }

    const int rbase = R0 + wave * 16 + quad * 4;
    #pragma unroll
    for (int t = 0; t < 4; ++t) {
        #pragma unroll
        for (int r = 0; r < 4; ++r) {
            const int rr = rbase + r;
            if (rr < N_NODES)
                pre[(size_t)rr * OUT_DIM + t * 16 + ln16] = f32_to_bf16(acc[t][r]);
        }
    }
}

// ---------------------------------------------------------------------------
// scan1: per-node degree = sum of 50 u16 chunk-partials, then prefix scan.
// (round-8 version, proven)
// ---------------------------------------------------------------------------
__global__ __launch_bounds__(256) void scan1_kernel(const unsigned short* __restrict__ partial,
                                                    int* __restrict__ off,
                                                    int* __restrict__ bsum) {
    __shared__ int s[256];
    const int t = threadIdx.x;
    const int base = blockIdx.x * 1024 + t * 4;
    int d[4] = {0, 0, 0, 0};
    for (int c = 0; c < HCH; ++c) {
        const u16x4 v = *(const u16x4*)(partial + (size_t)c * N_NODES + base);
        d[0] += v[0]; d[1] += v[1]; d[2] += v[2]; d[3] += v[3];
    }
    #pragma unroll
    for (int q = 0; q < 4; ++q)
        if (base + q >= N_NODES) d[q] = 0;
    const int tsum = d[0] + d[1] + d[2] + d[3];
    s[t] = tsum;
    __syncthreads();
    #pragma unroll
    for (int o = 1; o < 256; o <<= 1) {
        const int add = t >= o ? s[t - o] : 0;
        __syncthreads();
        s[t] += add;
        __syncthreads();
    }
    int run = t > 0 ? s[t - 1] : 0;
    #pragma unroll
    for (int q = 0; q < 4; ++q) {
        const int i = base + q;
        if (i < N_NODES) off[i] = run;
        run += d[q];
    }
    if (t == 255) bsum[blockIdx.x] = run;
}

__global__ __launch_bounds__(128) void scan2_kernel(const int* __restrict__ bsum,
                                                    int* __restrict__ boff,
                                                    int* __restrict__ off) {
    __shared__ int s[128];
    const int t = threadIdx.x;
    const int v = t < NB1 ? bsum[t] : 0;
    s[t] = v;
    __syncthreads();
    #pragma unroll
    for (int o = 1; o < 128; o <<= 1) {
        const int add = t >= o ? s[t - o] : 0;
        __syncthreads();
        s[t] += add;
        __syncthreads();
    }
    if (t < NB1) boff[t] = t > 0 ? s[t - 1] : 0;
    if (t == 127) off[N_NODES] = s[127];
}

__global__ __launch_bounds__(256) void scan3_kernel(int* __restrict__ off,
                                                    const int* __restrict__ boff,
                                                    int* __restrict__ cursor) {
    const int i = blockIdx.x * 256 + threadIdx.x;
    if (i < N_NODES) {
        const int v = off[i] + boff[i >> 10];
        off[i] = v;
        cursor[i] = v;
    }
}

// ---------------------------------------------------------------------------
// Reorder v4: PROVEN round-8 slot logic (global cursor atomics — order-
// agnostic, passed at 322us), reshaped for CO-RESIDENCY. Round-8 counters:
// WRITE_SIZE 76.5 MB vs 10.24 MB payload = 7.5x partial-line amplification.
// With 5000 blocks the ~12.8 writes filling a node's slot range were spread
// over 625 temporally disjoint block generations -> dirty lines evicted
// partial. Now 400 blocks (8 slices x 50 chunks of 25600 edges, 512 thr, no
// LDS) are ALL simultaneously resident; slice = blockIdx&7 pins each slice's
// writers to one XCD, so its 1.28 MB epack range fills inside one residency
// window. Streaming reads are NONTEMPORAL so they stop evicting dirty lines.
// (The round-9/10 zero-atomic cum scheme failed refcheck; shelved.)
// ---------------------------------------------------------------------------
__global__ __launch_bounds__(512) void reorder_kernel(const int* __restrict__ rows,
                                                      const int* __restrict__ cols,
                                                      const float* __restrict__ vals,
                                                      int* __restrict__ cursor,
                                                      unsigned long long* __restrict__ epack) {
    const int s = blockIdx.x & 7;                 // node-slice -> XCD pin
    const int c = blockIdx.x >> 3;                // edge chunk
    const int lo = s * RSN;
    const i32x4* rp = (const i32x4*)(rows + c * HEPC);
    const int nq = HEPC / 4;                      // 6400 int4 groups
    for (int i = threadIdx.x; i < nq; i += 512) {
        const i32x4 r4 = __builtin_nontemporal_load(rp + i);
        const int e0 = c * HEPC + i * 4;
        #pragma unroll
        for (int k = 0; k < 4; ++k) {
            const int r = r4[k];
            const unsigned d = (unsigned)(r - lo);
            if (d < RSN) {
                const int cc = __builtin_nontemporal_load(cols + e0 + k);
                const float vv = __builtin_nontemporal_load(vals + e0 + k);
                const int slot = atomicAdd(&cursor[r], 1);
                epack[slot] = ((unsigned long long)__float_as_uint(vv) << 32) | (unsigned int)cc;
            }
        }
    }
}

// ---------------------------------------------------------------------------
// Gather: one wave per node, lane = dim, 4-deep ILP. Fused bias + ReLU.
// ---------------------------------------------------------------------------
__global__ __launch_bounds__(256) void gather_kernel(const int* __restrict__ off,
                                                     const unsigned long long* __restrict__ epack,
                                                     const unsigned short* __restrict__ pre,
                                                     const float* __restrict__ bias,
                                                     float* __restrict__ out) {
    const int v = blockIdx.x * 4 + (threadIdx.x >> 6);
    const int j = threadIdx.x & 63;
    if (v >= N_NODES) return;
    const int s = off[v];
    const int e = off[v + 1];
    float acc = 0.0f;
    int i = s;
    for (; i + 4 <= e; i += 4) {
        unsigned long long ee[4];
        float p[4];
        #pragma unroll
        for (int q = 0; q < 4; ++q) ee[q] = epack[i + q];
        #pragma unroll
        for (int q = 0; q < 4; ++q)
            p[q] = bf16_to_f32(pre[(size_t)(unsigned int)(ee[q] & 0xffffffffu) * OUT_DIM + j]);
        #pragma unroll
        for (int q = 0; q < 4; ++q)
            acc = fmaf(p[q], __uint_as_float((unsigned int)(ee[q] >> 32)), acc);
    }
    for (; i < e; ++i) {
        const unsigned long long e0 = epack[i];
        acc = fmaf(bf16_to_f32(pre[(size_t)(unsigned int)(e0 & 0xffffffffu) * OUT_DIM + j]),
                   __uint_as_float((unsigned int)(e0 >> 32)), acc);
    }
    const float r = acc + bias[j];
    out[(size_t)v * OUT_DIM + j] = r > 0.0f ? r : 0.0f;
}

extern "C" void kernel_launch(void* const* d_in, const int* in_sizes, int n_in,
                              void* d_out, int out_size, void* d_ws, size_t ws_size,
                              hipStream_t stream) {
    const float* x    = (const float*)d_in[0];
    const int* rows   = (const int*)d_in[1];
    const int* cols   = (const int*)d_in[2];
    const float* vals = (const float*)d_in[3];
    const float* w    = (const float*)d_in[4];
    const float* bias = (const float*)d_in[5];
    float* out        = (float*)d_out;

    unsigned short* pre = (unsigned short*)d_ws;               // 12.8 MB bf16
    int* off    = (int*)(pre + (size_t)N_NODES * OUT_DIM);     // N_NODES+1 (+pad)
    int* cursor = off + N_NODES + 4;                           // 16B-aligned
    int* bsum   = cursor + N_NODES;                            // 128
    int* boff   = bsum + 128;                                  // 128
    unsigned long long* epack = (unsigned long long*)(boff + 128); // 10.24 MB, 8B-aligned

    // partial (10.0 MB u16) overlays epack: written by hist, read by scan1;
    // epack is only written later (reorder).
    unsigned short* partial = (unsigned short*)epack;
    // wbf (32 KB) overlays cursor: written by wpack, read by gemm; cursor is
    // only written later (scan3).
    unsigned short* wbf = (unsigned short*)cursor;

    wpack_kernel<<<16, 256, 0, stream>>>(w, wbf);

    hist_kernel<<<HSL * HCH, 256, 0, stream>>>(rows, partial);

    gemm_kernel<<<GEMM_BLOCKS, 256, 0, stream>>>(x, wbf, pre);

    scan1_kernel<<<NB1, 256, 0, stream>>>(partial, off, bsum);
    scan2_kernel<<<1, 128, 0, stream>>>(bsum, boff, off);
    scan3_kernel<<<(N_NODES + 255) / 256, 256, 0, stream>>>(off, boff, cursor);

    reorder_kernel<<<RSL * HCH, 512, 0, stream>>>(rows, cols, vals, cursor, epack);

    gather_kernel<<<(N_NODES + 3) / 4, 256, 0, stream>>>(off, epack, pre, bias, out);
}

// Round 12
// 328.714 us; speedup vs baseline: 1.0388x; 1.0388x over previous
//
#include <hip/hip_runtime.h>
#include <hip/hip_bf16.h>
#include <stdint.h>

#define N_NODES 100000
#define N_EDGES 1280000
#define IN_DIM  256
#define OUT_DIM 64
#define NB1     98          // ceil(100000/1024) scan blocks
#define GEMM_BLOCKS ((N_NODES + 63) / 64)   // 1563

// zero-global-atomic histogram: 4 bin-slices x 50 edge-chunks
#define HSL   4             // slices of 25000 bins (50 KB packed-u16 LDS)
#define HSB   25000         // bins per slice
#define HCH   50            // edge chunks
#define HEPC  (N_EDGES / HCH)   // 25600 edges per chunk (< 65536: u16-safe)

// reorder: 8 node-slices x 50 chunks, all 400 blocks co-resident
#define RSL   8
#define RSN   (N_NODES / RSL)    // 12500 nodes per slice (50 KB u32 LDS cursors)

typedef __attribute__((ext_vector_type(8))) short bf16x8;
typedef __attribute__((ext_vector_type(4))) float f32x4;
typedef __attribute__((ext_vector_type(4))) unsigned short u16x4;
typedef __attribute__((ext_vector_type(4))) int i32x4;

__device__ __forceinline__ unsigned short f32_to_bf16(float f) {
    union { float f; unsigned int u; } c; c.f = f;
    unsigned int u = c.u;
    u += 0x7fffu + ((u >> 16) & 1u);   // RNE
    return (unsigned short)(u >> 16);
}
__device__ __forceinline__ float bf16_to_f32(unsigned short h) {
    union { unsigned int u; float f; } c; c.u = ((unsigned int)h) << 16; return c.f;
}

// ---------------------------------------------------------------------------
// K0: one-time W pack (f32 -> bf16, B-fragment order), 16 blocks.
// ---------------------------------------------------------------------------
__global__ __launch_bounds__(256) void wpack_kernel(const float* __restrict__ w,
                                                    unsigned short* __restrict__ wbf) {
    const int i0 = blockIdx.x * 1024;
    for (int i = i0 + threadIdx.x; i < i0 + 1024; i += 256) {
        const int k = i >> 6, n = i & 63;
        const int kt = k >> 5, q = (k >> 3) & 3, j = k & 7;
        const int t = n >> 4, l = n & 15;
        wbf[((kt * 4 + t) * 64 + q * 16 + l) * 8 + j] = f32_to_bf16(w[i]);
    }
}

// ---------------------------------------------------------------------------
// K_hist: zero-global-atomic histogram (round-8, proven).
// ---------------------------------------------------------------------------
__global__ __launch_bounds__(256) void hist_kernel(const int* __restrict__ rows,
                                                   unsigned short* __restrict__ partial) {
    __shared__ unsigned int lh[HSB / 2];          // 50 KB
    const int s = blockIdx.x & 3;                 // slice
    const int c = blockIdx.x >> 2;                // chunk
    const int lo = s * HSB;
    for (int i = threadIdx.x; i < HSB / 2; i += 256) lh[i] = 0u;
    __syncthreads();
    const i32x4* rp = (const i32x4*)(rows + c * HEPC);
    for (int i = threadIdx.x; i < HEPC / 4; i += 256) {   // 25 iterations
        const i32x4 r4 = rp[i];
        const unsigned d0 = (unsigned)(r4.x - lo);
        const unsigned d1 = (unsigned)(r4.y - lo);
        const unsigned d2 = (unsigned)(r4.z - lo);
        const unsigned d3 = (unsigned)(r4.w - lo);
        if (d0 < HSB) atomicAdd(&lh[d0 >> 1], 1u << ((d0 & 1) * 16));
        if (d1 < HSB) atomicAdd(&lh[d1 >> 1], 1u << ((d1 & 1) * 16));
        if (d2 < HSB) atomicAdd(&lh[d2 >> 1], 1u << ((d2 & 1) * 16));
        if (d3 < HSB) atomicAdd(&lh[d3 >> 1], 1u << ((d3 & 1) * 16));
    }
    __syncthreads();
    unsigned int* dst = (unsigned int*)(partial + (size_t)c * N_NODES + lo);
    for (int i = threadIdx.x; i < HSB / 2; i += 256) dst[i] = lh[i];
}

// ---------------------------------------------------------------------------
// K1: GEMM (round-2 proven structure, unchanged).
// ---------------------------------------------------------------------------
__global__ __launch_bounds__(256, 4) void gemm_kernel(const float* __restrict__ x,
                                                      const unsigned short* __restrict__ wbf,
                                                      unsigned short* __restrict__ pre) {
    __shared__ __align__(16) unsigned short wt[IN_DIM * OUT_DIM];   // 32 KB

    const int tid = threadIdx.x;
    const int wave = tid >> 6;
    const int lane = tid & 63;
    const int ln16 = lane & 15;
    const int quad = lane >> 4;

    const int R0 = blockIdx.x * 64;
    const int arow = R0 + wave * 16 + ln16;
    const float* xrow = x + (size_t)(arow < N_NODES ? arow : N_NODES - 1) * IN_DIM + quad * 8;

    f32x4 xa[8], xb[8];
    #pragma unroll
    for (int kt = 0; kt < 8; ++kt) {
        xa[kt] = *(const f32x4*)(xrow + kt * 32);
        xb[kt] = *(const f32x4*)(xrow + kt * 32 + 4);
    }

    #pragma unroll
    for (int i = 0; i < 8; ++i)
        *(bf16x8*)&wt[i * 2048 + tid * 8] = *(const bf16x8*)(wbf + i * 2048 + tid * 8);

    __syncthreads();

    f32x4 acc[4] = {};

    #pragma unroll
    for (int kt = 0; kt < 8; ++kt) {
        bf16x8 a;
        a[0] = (short)f32_to_bf16(xa[kt].x); a[1] = (short)f32_to_bf16(xa[kt].y);
        a[2] = (short)f32_to_bf16(xa[kt].z); a[3] = (short)f32_to_bf16(xa[kt].w);
        a[4] = (short)f32_to_bf16(xb[kt].x); a[5] = (short)f32_to_bf16(xb[kt].y);
        a[6] = (short)f32_to_bf16(xb[kt].z); a[7] = (short)f32_to_bf16(xb[kt].w);
        #pragma unroll
        for (int t = 0; t < 4; ++t) {
            bf16x8 b = *(const bf16x8*)&wt[((kt * 4 + t) * 64 + lane) * 8];
            acc[t] = __builtin_amdgcn_mfma_f32_16x16x32_bf16(a, b, acc[t], 0, 0, 0);
        }
    }

    const int rbase = R0 + wave * 16 + quad * 4;
    #pragma unroll
    for (int t = 0; t < 4; ++t) {
        #pragma unroll
        for (int r = 0; r < 4; ++r) {
            const int rr = rbase + r;
            if (rr < N_NODES)
                pre[(size_t)rr * OUT_DIM + t * 16 + ln16] = f32_to_bf16(acc[t][r]);
        }
    }
}

// ---------------------------------------------------------------------------
// scan1: degree = sum of 50 u16 partials per node + write exclusive per-chunk
// prefix cum[c][v] (u16, d_out scratch). ROUND-12 FIX of the round-10
// failure: the cumt store is now BOUNDS-GUARDED. Round-10 wrote u16x4 at
// base in [100000,100348] (block 97), which lands in chunk c+1's stripe,
// nodes 0..348 — corrupting their prefixes (absmax 3.47, sparse). The
// partial READS at those indices are harmless (stay inside the buffer,
// values unused) and were present in the passing round-8 kernel.
// ---------------------------------------------------------------------------
__global__ __launch_bounds__(256) void scan1_kernel(const unsigned short* __restrict__ partial,
                                                    unsigned short* __restrict__ cumt,
                                                    int* __restrict__ off,
                                                    int* __restrict__ bsum) {
    __shared__ int s[256];
    const int t = threadIdx.x;
    const int base = blockIdx.x * 1024 + t * 4;
    const bool full = (base + 4 <= N_NODES);
    int d[4] = {0, 0, 0, 0};
    for (int c = 0; c < HCH; ++c) {
        const u16x4 v = *(const u16x4*)(partial + (size_t)c * N_NODES + base);
        if (full) {
            u16x4 pk;
            pk[0] = (unsigned short)d[0]; pk[1] = (unsigned short)d[1];
            pk[2] = (unsigned short)d[2]; pk[3] = (unsigned short)d[3];
            *(u16x4*)(cumt + (size_t)c * N_NODES + base) = pk;
        } else {
            #pragma unroll
            for (int q = 0; q < 4; ++q)
                if (base + q < N_NODES)
                    cumt[(size_t)c * N_NODES + base + q] = (unsigned short)d[q];
        }
        d[0] += v[0]; d[1] += v[1]; d[2] += v[2]; d[3] += v[3];
    }
    #pragma unroll
    for (int q = 0; q < 4; ++q)
        if (base + q >= N_NODES) d[q] = 0;
    const int tsum = d[0] + d[1] + d[2] + d[3];
    s[t] = tsum;
    __syncthreads();
    #pragma unroll
    for (int o = 1; o < 256; o <<= 1) {
        const int add = t >= o ? s[t - o] : 0;
        __syncthreads();
        s[t] += add;
        __syncthreads();
    }
    int run = t > 0 ? s[t - 1] : 0;
    #pragma unroll
    for (int q = 0; q < 4; ++q) {
        const int i = base + q;
        if (i < N_NODES) off[i] = run;
        run += d[q];
    }
    if (t == 255) bsum[blockIdx.x] = run;
}

__global__ __launch_bounds__(128) void scan2_kernel(const int* __restrict__ bsum,
                                                    int* __restrict__ boff,
                                                    int* __restrict__ off) {
    __shared__ int s[128];
    const int t = threadIdx.x;
    const int v = t < NB1 ? bsum[t] : 0;
    s[t] = v;
    __syncthreads();
    #pragma unroll
    for (int o = 1; o < 128; o <<= 1) {
        const int add = t >= o ? s[t - o] : 0;
        __syncthreads();
        s[t] += add;
        __syncthreads();
    }
    if (t < NB1) boff[t] = t > 0 ? s[t - 1] : 0;
    if (t == 127) off[N_NODES] = s[127];
}

__global__ __launch_bounds__(256) void scan3_kernel(int* __restrict__ off,
                                                    const int* __restrict__ boff) {
    const int i = blockIdx.x * 256 + threadIdx.x;
    if (i < N_NODES) off[i] += boff[i >> 10];
}

// ---------------------------------------------------------------------------
// Reorder v5: zero global atomics, deterministic slots. Block (slice s,
// chunk c): LDS rank cursor per slice node; slot = off[r] + cum[c][r] + rank
// — disjoint complete tiling of [off[r], off[r]+deg[r]). PLAIN loads
// (round-11 measured nontemporal inflates FETCH +19 MB: rows' 8x re-read
// stopped hitting LLC). 400 co-resident blocks keep write-combining.
// Removes the 1.28M cursor atomic round-trips (~20 MB RMW + serialization).
// ---------------------------------------------------------------------------
__global__ __launch_bounds__(512) void reorder_kernel(const int* __restrict__ rows,
                                                      const int* __restrict__ cols,
                                                      const float* __restrict__ vals,
                                                      const int* __restrict__ off,
                                                      const unsigned short* __restrict__ cumt,
                                                      unsigned long long* __restrict__ epack) {
    __shared__ unsigned int lcur[RSN];            // 50 KB rank cursors
    const int s = blockIdx.x & 7;                 // node-slice -> XCD pin
    const int c = blockIdx.x >> 3;                // edge chunk
    const int lo = s * RSN;
    for (int i = threadIdx.x; i < RSN; i += 512) lcur[i] = 0u;
    __syncthreads();
    const i32x4* rp = (const i32x4*)(rows + c * HEPC);
    const unsigned short* cumc = cumt + (size_t)c * N_NODES;
    const int nq = HEPC / 4;                      // 6400 int4 groups
    for (int i = threadIdx.x; i < nq; i += 512) {
        const i32x4 r4 = rp[i];
        const int e0 = c * HEPC + i * 4;
        #pragma unroll
        for (int k = 0; k < 4; ++k) {
            const int r = r4[k];
            const unsigned d = (unsigned)(r - lo);
            if (d < RSN) {
                const int cc = cols[e0 + k];
                const float vv = vals[e0 + k];
                const unsigned rank = atomicAdd(&lcur[d], 1u);
                const int slot = off[r] + (int)cumc[r] + (int)rank;
                epack[slot] = ((unsigned long long)__float_as_uint(vv) << 32) | (unsigned int)cc;
            }
        }
    }
}

// ---------------------------------------------------------------------------
// Gather: one wave per node, lane = dim, 4-deep ILP. Fused bias + ReLU.
// ---------------------------------------------------------------------------
__global__ __launch_bounds__(256) void gather_kernel(const int* __restrict__ off,
                                                     const unsigned long long* __restrict__ epack,
                                                     const unsigned short* __restrict__ pre,
                                                     const float* __restrict__ bias,
                                                     float* __restrict__ out) {
    const int v = blockIdx.x * 4 + (threadIdx.x >> 6);
    const int j = threadIdx.x & 63;
    if (v >= N_NODES) return;
    const int s = off[v];
    const int e = off[v + 1];
    float acc = 0.0f;
    int i = s;
    for (; i + 4 <= e; i += 4) {
        unsigned long long ee[4];
        float p[4];
        #pragma unroll
        for (int q = 0; q < 4; ++q) ee[q] = epack[i + q];
        #pragma unroll
        for (int q = 0; q < 4; ++q)
            p[q] = bf16_to_f32(pre[(size_t)(unsigned int)(ee[q] & 0xffffffffu) * OUT_DIM + j]);
        #pragma unroll
        for (int q = 0; q < 4; ++q)
            acc = fmaf(p[q], __uint_as_float((unsigned int)(ee[q] >> 32)), acc);
    }
    for (; i < e; ++i) {
        const unsigned long long e0 = epack[i];
        acc = fmaf(bf16_to_f32(pre[(size_t)(unsigned int)(e0 & 0xffffffffu) * OUT_DIM + j]),
                   __uint_as_float((unsigned int)(e0 >> 32)), acc);
    }
    const float r = acc + bias[j];
    out[(size_t)v * OUT_DIM + j] = r > 0.0f ? r : 0.0f;
}

extern "C" void kernel_launch(void* const* d_in, const int* in_sizes, int n_in,
                              void* d_out, int out_size, void* d_ws, size_t ws_size,
                              hipStream_t stream) {
    const float* x    = (const float*)d_in[0];
    const int* rows   = (const int*)d_in[1];
    const int* cols   = (const int*)d_in[2];
    const float* vals = (const float*)d_in[3];
    const float* w    = (const float*)d_in[4];
    const float* bias = (const float*)d_in[5];
    float* out        = (float*)d_out;

    unsigned short* pre = (unsigned short*)d_ws;               // 12.8 MB bf16
    int* off    = (int*)(pre + (size_t)N_NODES * OUT_DIM);     // N_NODES+1 (+pad)
    int* cursor = off + N_NODES + 4;                           // (dead; holds wbf)
    int* bsum   = cursor + N_NODES;                            // 128
    int* boff   = bsum + 128;                                  // 128
    unsigned long long* epack = (unsigned long long*)(boff + 128); // 10.24 MB, 8B-aligned

    // partial (10.0 MB u16) overlays epack: written by hist, read by scan1;
    // epack is only written later (reorder).
    unsigned short* partial = (unsigned short*)epack;
    // wbf (32 KB) overlays the dead cursor region.
    unsigned short* wbf = (unsigned short*)cursor;
    // cum table (10.0 MB u16) lives in d_out: harness memsets out BEFORE
    // launch; scan1 writes it, reorder reads it, gather fully overwrites out.
    unsigned short* cumt = (unsigned short*)out;

    wpack_kernel<<<16, 256, 0, stream>>>(w, wbf);

    hist_kernel<<<HSL * HCH, 256, 0, stream>>>(rows, partial);

    gemm_kernel<<<GEMM_BLOCKS, 256, 0, stream>>>(x, wbf, pre);

    scan1_kernel<<<NB1, 256, 0, stream>>>(partial, cumt, off, bsum);
    scan2_kernel<<<1, 128, 0, stream>>>(bsum, boff, off);
    scan3_kernel<<<(N_NODES + 255) / 256, 256, 0, stream>>>(off, boff);

    reorder_kernel<<<RSL * HCH, 512, 0, stream>>>(rows, cols, vals, off, cumt, epack);

    gather_kernel<<<(N_NODES + 3) / 4, 256, 0, stream>>>(off, epack, pre, bias, out);
}